// Round 8
// baseline (817.825 us; speedup 1.0000x reference)
//
#include <hip/hip_runtime.h>
#include <hip/hip_bf16.h>
#include <math.h>

#define BATCH  64
#define SEQ    2048
#define DMODEL 512
#define ATT    256
#define M_TOTAL (BATCH * SEQ)

#define MT     256                      // rows per block (scores GEMM)
#define KC     32                       // k per chunk
#define NCHUNK 16
#define BCH    (ATT * KC)               // 8192 ushorts = 16 KB per B half-tile
#define WA_LO_OFF (NCHUNK * BCH)        // 131072 ushorts

// d_ws layout
#define XH_OFF    (1u << 20)                          // 1 MB (wa_cvt lives below)
#define XH_BYTES  ((size_t)M_TOTAL * DMODEL * 2)      // 128 MB bf16 X-hi
#define PART_OFF  (XH_OFF + XH_BYTES)
#define PART_BYTES ((size_t)8 * BATCH * DMODEL * 4)   // 1 MB
#define WS_NEED   (PART_OFF + PART_BYTES)

typedef __attribute__((ext_vector_type(8))) short short8v;
typedef __attribute__((ext_vector_type(4))) float floatx4;

__device__ __forceinline__ ushort f2bf_rne(float f) {
    unsigned u = __float_as_uint(f);
    u += 0x7FFFu + ((u >> 16) & 1u);
    return (ushort)(u >> 16);
}
__device__ __forceinline__ float bf2f(ushort h) {
    return __uint_as_float(((unsigned)h) << 16);
}
__device__ __forceinline__ void gll16(const void* g, void* l) {
    __builtin_amdgcn_global_load_lds(
        (const __attribute__((address_space(1))) unsigned*)g,
        (__attribute__((address_space(3))) unsigned*)l, 16, 0, 0);
}
// sign-free fast tanh: 1 - 2/(e^{2x}+1); exact at +-inf, 0
__device__ __forceinline__ float fast_tanh(float x) {
    return 1.0f - 2.0f * __builtin_amdgcn_rcpf(__expf(x + x) + 1.0f);
}
// float4 -> packed bf16 hi (truncation) + lo (RNE of remainder)
__device__ __forceinline__ void cvt4(float4 v, uint2& hi, uint2& lo) {
    unsigned u0 = __float_as_uint(v.x), u1 = __float_as_uint(v.y);
    unsigned u2 = __float_as_uint(v.z), u3 = __float_as_uint(v.w);
    hi.x = __builtin_amdgcn_perm(u1, u0, 0x07060302u);   // [bf(y):bf(x)]
    hi.y = __builtin_amdgcn_perm(u3, u2, 0x07060302u);
    float r0 = v.x - __uint_as_float(u0 & 0xFFFF0000u);
    float r1 = v.y - __uint_as_float(u1 & 0xFFFF0000u);
    float r2 = v.z - __uint_as_float(u2 & 0xFFFF0000u);
    float r3 = v.w - __uint_as_float(u3 & 0xFFFF0000u);
    asm("v_cvt_pk_bf16_f32 %0, %1, %2" : "=v"(lo.x) : "v"(r0), "v"(r1));
    asm("v_cvt_pk_bf16_f32 %0, %1, %2" : "=v"(lo.y) : "v"(r2), "v"(r3));
}
// 8 floats -> hi/lo short8v images (k-order preserved: low ushort = first elem)
__device__ __forceinline__ void cvt8(float4 a, float4 b, uint4& hi, uint4& lo) {
    uint2 h0, l0, h1, l1;
    cvt4(a, h0, l0);
    cvt4(b, h1, l1);
    hi = make_uint4(h0.x, h0.y, h1.x, h1.y);
    lo = make_uint4(l0.x, l0.y, l1.x, l1.y);
}

// K0: Wa fp32 [256][512] -> bf16 hi/lo per-chunk quad-major LDS images:
// elem (a, k): chunk kc=k>>5, quad q=(k&31)>>3 -> kc*8192 + (q*256+a)*8 + (k&7)
__global__ __launch_bounds__(256)
void wa_convert_kernel(const float* __restrict__ Wa, ushort* __restrict__ out) {
    int idx = blockIdx.x * 256 + threadIdx.x;   // 131072
    float x = Wa[idx];
    ushort hi = f2bf_rne(x);
    ushort lo = f2bf_rne(x - bf2f(hi));
    int a = idx >> 9, k = idx & 511;
    int kc = k >> 5, kk = k & 31, q = kk >> 3;
    size_t o = (size_t)kc * BCH + (size_t)(q * 256 + a) * 8 + (kk & 7);
    out[o] = hi;
    out[WA_LO_OFF + o] = lo;
}

// B-chunk staging: 4 gll16 per thread (linear copy of prebuilt swizzled image)
__device__ __forceinline__ void gll_b(ushort* nb, int chunk,
                                      const ushort* __restrict__ wa_cvt,
                                      int wid, int l) {
    ushort* bh = nb;
    ushort* bl = nb + BCH;
    const char* ghi = (const char*)(wa_cvt + (size_t)chunk * BCH);
    const char* glo = (const char*)(wa_cvt + (size_t)WA_LO_OFF + (size_t)chunk * BCH);
    #pragma unroll
    for (int i = 0; i < 2; ++i) {
        int seg = wid * 2 + i;                  // 16 segs x 1 KB per half
        gll16(ghi + seg * 1024 + l * 16, (char*)bh + seg * 1024);
        gll16(glo + seg * 1024 + l * 16, (char*)bl + seg * 1024);
    }
}

#define SB() __builtin_amdgcn_sched_barrier(0)
// 3-term split MFMA for one output column-block nj
#define MFMA3(nj, BH, BV)                                                           \
    {                                                                               \
        _Pragma("unroll")                                                           \
        for (int mi = 0; mi < 4; ++mi) {                                            \
            acc[mi][nj] = __builtin_amdgcn_mfma_f32_16x16x32_bf16(av[mi], BH, acc[mi][nj], 0, 0, 0); \
            acc[mi][nj] = __builtin_amdgcn_mfma_f32_16x16x32_bf16(ah[mi], BV, acc[mi][nj], 0, 0, 0); \
            acc[mi][nj] = __builtin_amdgcn_mfma_f32_16x16x32_bf16(ah[mi], BH, acc[mi][nj], 0, 0, 0); \
        }                                                                           \
    }

// K1: z[m] = sum_a tanh(X[m]·Wa[a] + ba[a]) * ae[a], split-bf16 3-term MFMA.
// A-operand DIRECT from global (per-lane fragment loads, converted in regs);
// B via 2x32KB double-buffered LDS. 512 thr / 8 waves; 64 KB LDS -> 2 blocks/CU.
__global__ __launch_bounds__(512, 4)
void scores_mfma_kernel(const float* __restrict__ X,
                        const ushort* __restrict__ wa_cvt,
                        const float* __restrict__ ba,
                        const float* __restrict__ ae,
                        float* __restrict__ z,
                        ushort* __restrict__ Xh) {
    __shared__ __align__(16) ushort pool[2][2 * BCH];   // 64 KiB

    const int tid = threadIdx.x;
    const int l   = tid & 63;
    const int wid = tid >> 6;
    const int wm  = wid >> 1, wn = wid & 1;
    const int n   = l & 15,   g  = l >> 4;
    const int m0  = blockIdx.x * MT;

    // A fragment source: lane row = m0 + wm*64 + mi*16 + n, k = kc*32 + g*8
    const size_t arow0 = (size_t)(m0 + wm * 64 + n);
    const float* xb = X + arow0 * DMODEL + g * 8;
    ushort* xhb = Xh ? (Xh + arow0 * DMODEL + g * 8) : nullptr;

    // B frag base in quad-major half-tile: (g*256 + wn*128 + n)*8 + nj*128
    const int bb = g * 2048 + (wn * 128 + n) * 8;

    floatx4 acc[4][8];
    #pragma unroll
    for (int i = 0; i < 4; ++i)
        #pragma unroll
        for (int j = 0; j < 8; ++j)
            acc[i][j] = (floatx4){0.f, 0.f, 0.f, 0.f};

    // ---- prologue: gll B chunk 0, issue A chunk-0 loads ----
    float4 xr[4][2];
    gll_b(&pool[0][0], 0, wa_cvt, wid, l);
    SB();
    #pragma unroll
    for (int mi = 0; mi < 4; ++mi) {
        xr[mi][0] = *(const float4*)(xb + mi * 16 * DMODEL);
        xr[mi][1] = *(const float4*)(xb + mi * 16 * DMODEL + 4);
    }
    asm volatile("s_waitcnt vmcnt(8)" ::: "memory");   // drain glls; A flies
    __builtin_amdgcn_s_barrier();

    #pragma unroll 1
    for (int kc = 0; kc < NCHUNK; ++kc) {
        const ushort* bh_t = &pool[kc & 1][0];
        const ushort* bl_t = bh_t + BCH;
        ushort* nxt = &pool[(kc + 1) & 1][0];
        const bool more = (kc + 1 < NCHUNK);

        // stage next B chunk first (max in-flight time)
        if (more) gll_b(nxt, kc + 1, wa_cvt, wid, l);
        SB();

        // B pair0 reads + convert A (xr wait overlaps other waves' compute)
        short8v b0h = *(const short8v*)&bh_t[bb      ];
        short8v b0v = *(const short8v*)&bl_t[bb      ];
        short8v b1h = *(const short8v*)&bh_t[bb + 128];
        short8v b1v = *(const short8v*)&bl_t[bb + 128];
        short8v ah[4], av[4];
        #pragma unroll
        for (int mi = 0; mi < 4; ++mi)
            cvt8(xr[mi][0], xr[mi][1], *(uint4*)&ah[mi], *(uint4*)&av[mi]);
        // Xh side-write (bf16-hi of this chunk's fragments; full coverage by wn=0/1 dup)
        if (xhb && wn == 0) {
            #pragma unroll
            for (int mi = 0; mi < 4; ++mi)
                *(uint4*)(xhb + mi * 16 * DMODEL + kc * KC) = *(uint4*)&ah[mi];
        }
        SB();

        // phase 0: prefetch B pair1; MFMA pair0
        short8v b2h = *(const short8v*)&bh_t[bb + 256];
        short8v b2v = *(const short8v*)&bl_t[bb + 256];
        short8v b3h = *(const short8v*)&bh_t[bb + 384];
        short8v b3v = *(const short8v*)&bl_t[bb + 384];
        __builtin_amdgcn_s_setprio(1);
        MFMA3(0, b0h, b0v);
        MFMA3(1, b1h, b1v);
        __builtin_amdgcn_s_setprio(0);
        SB();

        // phase 1: prefetch B pair2; MFMA pair1
        b0h = *(const short8v*)&bh_t[bb + 512];
        b0v = *(const short8v*)&bl_t[bb + 512];
        b1h = *(const short8v*)&bh_t[bb + 640];
        b1v = *(const short8v*)&bl_t[bb + 640];
        __builtin_amdgcn_s_setprio(1);
        MFMA3(2, b2h, b2v);
        MFMA3(3, b3h, b3v);
        __builtin_amdgcn_s_setprio(0);
        SB();

        // issue A loads for next chunk (held in xr across phases 2-3)
        if (more) {
            #pragma unroll
            for (int mi = 0; mi < 4; ++mi) {
                xr[mi][0] = *(const float4*)(xb + mi * 16 * DMODEL + (kc + 1) * KC);
                xr[mi][1] = *(const float4*)(xb + mi * 16 * DMODEL + (kc + 1) * KC + 4);
            }
        }
        SB();

        // phase 2: prefetch B pair3; MFMA pair2
        b2h = *(const short8v*)&bh_t[bb + 768];
        b2v = *(const short8v*)&bl_t[bb + 768];
        b3h = *(const short8v*)&bh_t[bb + 896];
        b3v = *(const short8v*)&bl_t[bb + 896];
        __builtin_amdgcn_s_setprio(1);
        MFMA3(4, b0h, b0v);
        MFMA3(5, b1h, b1v);
        __builtin_amdgcn_s_setprio(0);
        SB();

        // phase 3: MFMA pair3; counted drain (gll+stores) + barrier; A stays in flight
        __builtin_amdgcn_s_setprio(1);
        MFMA3(6, b2h, b2v);
        MFMA3(7, b3h, b3v);
        __builtin_amdgcn_s_setprio(0);
        SB();
        if (more) {
            asm volatile("s_waitcnt vmcnt(8)" ::: "memory");
            __builtin_amdgcn_s_barrier();
        }
    }

    __syncthreads();                     // all compute done; pool reusable
    float* zb = (float*)&pool[0][0];     // [2][256] partial z

    float bav[8], aev[8];
    #pragma unroll
    for (int nj = 0; nj < 8; ++nj) {
        int c = wn * 128 + nj * 16 + n;
        bav[nj] = ba[c];
        aev[nj] = ae[c];
    }
    // C/D map (HW-verified): M-row = wm*64 + mi*16 + g*4 + e, col = wn*128 + nj*16 + n
    #pragma unroll
    for (int mi = 0; mi < 4; ++mi) {
        float zp[4] = {0.f, 0.f, 0.f, 0.f};
        #pragma unroll
        for (int nj = 0; nj < 8; ++nj)
            #pragma unroll
            for (int e = 0; e < 4; ++e)
                zp[e] += fast_tanh(acc[mi][nj][e] + bav[nj]) * aev[nj];
        #pragma unroll
        for (int off = 8; off >= 1; off >>= 1)
            #pragma unroll
            for (int e = 0; e < 4; ++e)
                zp[e] += __shfl_xor(zp[e], off, 64);
        if (n == 0)
            *(float4*)&zb[wn * 256 + wm * 64 + mi * 16 + g * 4] =
                make_float4(zp[0], zp[1], zp[2], zp[3]);
    }
    __syncthreads();
    if (tid < MT)
        z[m0 + tid] = zb[tid] + zb[256 + tid];
}

// K2: in-place softmax over SEQ per batch.
__global__ __launch_bounds__(256)
void softmax_kernel(float* __restrict__ zw) {
    __shared__ float red[4];
    __shared__ float bcast;
    const int b = blockIdx.x, tid = threadIdx.x;
    float* row = zw + (size_t)b * SEQ;

    float zi[8];
    #pragma unroll
    for (int i = 0; i < 8; ++i) zi[i] = row[tid + i * 256];

    float m = -3.0e38f;
    #pragma unroll
    for (int i = 0; i < 8; ++i) m = fmaxf(m, zi[i]);
    #pragma unroll
    for (int off = 32; off >= 1; off >>= 1) m = fmaxf(m, __shfl_xor(m, off, 64));
    if ((tid & 63) == 0) red[tid >> 6] = m;
    __syncthreads();
    if (tid == 0) bcast = fmaxf(fmaxf(red[0], red[1]), fmaxf(red[2], red[3]));
    __syncthreads();
    m = bcast;

    float s = 0.f;
    #pragma unroll
    for (int i = 0; i < 8; ++i) { zi[i] = expf(zi[i] - m); s += zi[i]; }
    #pragma unroll
    for (int off = 32; off >= 1; off >>= 1) s += __shfl_xor(s, off, 64);
    __syncthreads();
    if ((tid & 63) == 0) red[tid >> 6] = s;
    __syncthreads();
    if (tid == 0) bcast = 1.f / (red[0] + red[1] + red[2] + red[3]);
    __syncthreads();
    float inv = bcast;

    #pragma unroll
    for (int i = 0; i < 8; ++i) row[tid + i * 256] = zi[i] * inv;
}

// K3a: bf16 pool partials: partials[sc][b][f] = sum_{s in chunk} w[s]*Xh[b,s,f]
#define PCHUNK 256
__global__ __launch_bounds__(512)
void pool_bf16_kernel(const ushort* __restrict__ Xh, const float* __restrict__ w,
                      float* __restrict__ partials) {
    __shared__ float wl[PCHUNK];
    __shared__ float2 accs[512];
    const int b  = blockIdx.y;
    const int sc = blockIdx.x;       // 0..7
    const int t  = threadIdx.x;
    const int u  = t & 255;          // uint idx: features 2u, 2u+1
    const int p  = t >> 8;           // row parity
    const int s0 = sc * PCHUNK;
    if (t < PCHUNK) wl[t] = w[(size_t)b * SEQ + s0 + t];
    __syncthreads();
    const uint* xp = (const uint*)(Xh + ((size_t)b * SEQ + s0 + p) * DMODEL) + u;
    float a0 = 0.f, a1 = 0.f;
    #pragma unroll 8
    for (int s = 0; s < PCHUNK; s += 2) {
        uint v   = xp[(size_t)s * (DMODEL / 2)];
        float ws = wl[s + p];
        a0 = fmaf(__uint_as_float(v << 16), ws, a0);
        a1 = fmaf(__uint_as_float(v & 0xFFFF0000u), ws, a1);
    }
    accs[t] = make_float2(a0, a1);
    __syncthreads();
    if (t < 256) {
        float2 x0 = accs[t], x1 = accs[t + 256];
        *(float2*)&partials[((size_t)sc * BATCH + b) * DMODEL + 2 * t] =
            make_float2(x0.x + x1.x, x0.y + x1.y);
    }
}

// K3b: out[b][f] = sum_sc partials[sc][b][f]
__global__ __launch_bounds__(512)
void pool_reduce_kernel(const float* __restrict__ partials, float* __restrict__ out) {
    int i = blockIdx.x * 512 + threadIdx.x;   // 32768
    float s = 0.f;
    #pragma unroll
    for (int c = 0; c < 8; ++c)
        s += partials[(size_t)c * BATCH * DMODEL + i];
    out[i] = s;
}

// fallback fp32 pool (if ws too small): needs memset + atomics
__global__ __launch_bounds__(512)
void pool_fp32_kernel(const float* __restrict__ X, const float* __restrict__ w,
                      float* __restrict__ out) {
    __shared__ float wl[PCHUNK];
    const int b  = blockIdx.y;
    const int sc = blockIdx.x;
    const int f  = threadIdx.x;
    const int s0 = sc * PCHUNK;
    if (f < PCHUNK) wl[f] = w[(size_t)b * SEQ + s0 + f];
    __syncthreads();
    const float* xp = X + ((size_t)b * SEQ + s0) * DMODEL + f;
    float a0 = 0.f, a1 = 0.f, a2 = 0.f, a3 = 0.f;
    #pragma unroll 4
    for (int s = 0; s < PCHUNK; s += 4) {
        a0 = fmaf(xp[(size_t)(s + 0) * DMODEL], wl[s + 0], a0);
        a1 = fmaf(xp[(size_t)(s + 1) * DMODEL], wl[s + 1], a1);
        a2 = fmaf(xp[(size_t)(s + 2) * DMODEL], wl[s + 2], a2);
        a3 = fmaf(xp[(size_t)(s + 3) * DMODEL], wl[s + 3], a3);
    }
    atomicAdd(&out[b * DMODEL + f], (a0 + a1) + (a2 + a3));
}

extern "C" void kernel_launch(void* const* d_in, const int* in_sizes, int n_in,
                              void* d_out, int out_size, void* d_ws, size_t ws_size,
                              hipStream_t stream) {
    const float* X  = (const float*)d_in[0];
    const float* Wa = (const float*)d_in[1];
    const float* ba = (const float*)d_in[2];
    const float* ae = (const float*)d_in[3];
    float* out  = (float*)d_out;
    float* feat = out;                       // [64][512]
    float* wgt  = out + BATCH * DMODEL;      // [64][2048]; z pre-softmax

    ushort* wa_cvt = (ushort*)d_ws;          // 512 KB
    const bool big_ws = ws_size >= WS_NEED;
    ushort* Xh      = big_ws ? (ushort*)((char*)d_ws + XH_OFF)  : nullptr;
    float* partials = big_ws ? (float*)((char*)d_ws + PART_OFF) : nullptr;

    wa_convert_kernel<<<ATT * DMODEL / 256, 256, 0, stream>>>(Wa, wa_cvt);
    scores_mfma_kernel<<<M_TOTAL / MT, 512, 0, stream>>>(X, wa_cvt, ba, ae, wgt, Xh);
    softmax_kernel<<<BATCH, 256, 0, stream>>>(wgt);
    if (big_ws) {
        pool_bf16_kernel<<<dim3(SEQ / PCHUNK, BATCH), 512, 0, stream>>>(Xh, wgt, partials);
        pool_reduce_kernel<<<BATCH * DMODEL / 512, 512, 0, stream>>>(partials, feat);
    } else {
        hipMemsetAsync(feat, 0, BATCH * DMODEL * sizeof(float), stream);
        pool_fp32_kernel<<<dim3(SEQ / PCHUNK, BATCH), 512, 0, stream>>>(X, wgt, feat);
    }
}

// Round 9
// 221.995 us; speedup vs baseline: 3.6840x; 3.6840x over previous
//
#include <hip/hip_runtime.h>
#include <hip/hip_bf16.h>
#include <math.h>

#define BATCH  64
#define SEQ    2048
#define DMODEL 512
#define ATT    256
#define M_TOTAL (BATCH * SEQ)

#define MT     64                       // rows per block (scores GEMM)
#define KC     32                       // k per chunk
#define NCHUNK 16
#define BCH    (ATT * KC)               // 8192 ushorts = 16 KB per B half-image
#define WA_LO_OFF (NCHUNK * BCH)        // 131072 ushorts

// d_ws layout
#define XH_OFF    (1u << 20)                          // 1 MB (wa_cvt lives below)
#define XH_BYTES  ((size_t)M_TOTAL * DMODEL * 2)      // 128 MB bf16 X-hi
#define PART_OFF  (XH_OFF + XH_BYTES)
#define PART_BYTES ((size_t)8 * BATCH * DMODEL * 4)   // 1 MB
#define WS_NEED   (PART_OFF + PART_BYTES)

typedef __attribute__((ext_vector_type(8))) short short8v;
typedef __attribute__((ext_vector_type(4))) float floatx4;

__device__ __forceinline__ ushort f2bf_rne(float f) {
    unsigned u = __float_as_uint(f);
    u += 0x7FFFu + ((u >> 16) & 1u);
    return (ushort)(u >> 16);
}
__device__ __forceinline__ float bf2f(ushort h) {
    return __uint_as_float(((unsigned)h) << 16);
}
// sign-free fast tanh: 1 - 2/(e^{2x}+1); exact at +-inf, 0
__device__ __forceinline__ float fast_tanh(float x) {
    return 1.0f - 2.0f * __builtin_amdgcn_rcpf(__expf(x + x) + 1.0f);
}
// float4 -> packed bf16 hi (truncation) + lo (RNE of remainder)
__device__ __forceinline__ void cvt4(float4 v, uint2& hi, uint2& lo) {
    unsigned u0 = __float_as_uint(v.x), u1 = __float_as_uint(v.y);
    unsigned u2 = __float_as_uint(v.z), u3 = __float_as_uint(v.w);
    hi.x = __builtin_amdgcn_perm(u1, u0, 0x07060302u);   // [bf(y):bf(x)]
    hi.y = __builtin_amdgcn_perm(u3, u2, 0x07060302u);
    float r0 = v.x - __uint_as_float(u0 & 0xFFFF0000u);
    float r1 = v.y - __uint_as_float(u1 & 0xFFFF0000u);
    float r2 = v.z - __uint_as_float(u2 & 0xFFFF0000u);
    float r3 = v.w - __uint_as_float(u3 & 0xFFFF0000u);
    asm("v_cvt_pk_bf16_f32 %0, %1, %2" : "=v"(lo.x) : "v"(r0), "v"(r1));
    asm("v_cvt_pk_bf16_f32 %0, %1, %2" : "=v"(lo.y) : "v"(r2), "v"(r3));
}
// 8 floats -> hi/lo packed images (k-order preserved)
__device__ __forceinline__ void cvt8(float4 a, float4 b, uint4& hi, uint4& lo) {
    uint2 h0, l0, h1, l1;
    cvt4(a, h0, l0);
    cvt4(b, h1, l1);
    hi = make_uint4(h0.x, h0.y, h1.x, h1.y);
    lo = make_uint4(l0.x, l0.y, l1.x, l1.y);
}

// K0: Wa fp32 [256][512] -> bf16 hi/lo per-chunk quad-major images:
// elem (a, k): chunk kc=k>>5, quad q=(k&31)>>3 -> kc*8192 + (q*256+a)*8 + (k&7)
// B fragment for (col, g, kc) = 16 contiguous bytes at (g*256+col)*8 ushorts.
__global__ __launch_bounds__(256)
void wa_convert_kernel(const float* __restrict__ Wa, ushort* __restrict__ out) {
    int idx = blockIdx.x * 256 + threadIdx.x;   // 131072
    float x = Wa[idx];
    ushort hi = f2bf_rne(x);
    ushort lo = f2bf_rne(x - bf2f(hi));
    int a = idx >> 9, k = idx & 511;
    int kc = k >> 5, kk = k & 31, q = kk >> 3;
    size_t o = (size_t)kc * BCH + (size_t)(q * 256 + a) * 8 + (kk & 7);
    out[o] = hi;
    out[WA_LO_OFF + o] = lo;
}

// K1: z[m] = sum_a tanh(X[m]·Wa[a] + ba[a]) * ae[a], split-bf16 3-term MFMA.
// NO LDS staging, NO barriers: A fragments direct from X (L1-shared across
// waves), B fragments direct from the L2-resident quad-major images.
// 256 thr / 4 waves; wave w owns cols [w*64, w*64+64); block = 64 rows.
__global__ __launch_bounds__(256, 3)
void scores_mfma_kernel(const float* __restrict__ X,
                        const ushort* __restrict__ wa_cvt,
                        const float* __restrict__ ba,
                        const float* __restrict__ ae,
                        float* __restrict__ z,
                        ushort* __restrict__ Xh) {
    __shared__ float zb[4][MT];          // epilogue cross-wave reduce only

    const int tid = threadIdx.x;
    const int l   = tid & 63;
    const int wid = tid >> 6;
    const int n   = l & 15, g = l >> 4;
    const int m0  = blockIdx.x * MT;

    // A source: lane row = m0 + mi*16 + n, k-window = kc*32 + g*8 .. +8
    const float* xb = X + (size_t)(m0 + n) * DMODEL + g * 8;
    ushort* xhb = Xh ? (Xh + (size_t)(m0 + n) * DMODEL + g * 8) : nullptr;

    // B source: frag(col, g, kc) at wa_cvt + kc*BCH + (g*256 + col)*8
    const ushort* bsrc = wa_cvt + (size_t)(g * 256 + wid * 64 + n) * 8;

    floatx4 acc[4][4];
    #pragma unroll
    for (int i = 0; i < 4; ++i)
        #pragma unroll
        for (int j = 0; j < 4; ++j)
            acc[i][j] = (floatx4){0.f, 0.f, 0.f, 0.f};

    // prefetch chunk-0 A
    float4 xr0[4], xr1[4];
    #pragma unroll
    for (int mi = 0; mi < 4; ++mi) {
        xr0[mi] = *(const float4*)(xb + (size_t)mi * 16 * DMODEL);
        xr1[mi] = *(const float4*)(xb + (size_t)mi * 16 * DMODEL + 4);
    }

    #pragma unroll 1
    for (int kc = 0; kc < NCHUNK; ++kc) {
        // convert A fragments for this chunk
        short8v ah[4], av[4];
        #pragma unroll
        for (int mi = 0; mi < 4; ++mi)
            cvt8(xr0[mi], xr1[mi], *(uint4*)&ah[mi], *(uint4*)&av[mi]);

        // Xh side-write: wave 0 covers all 64 rows x this chunk's k-window
        if (xhb && wid == 0) {
            #pragma unroll
            for (int mi = 0; mi < 4; ++mi)
                *(uint4*)(xhb + (size_t)mi * 16 * DMODEL + kc * KC) = *(uint4*)&ah[mi];
        }

        // prefetch next-chunk A (HBM latency hides under this chunk's MFMAs)
        if (kc + 1 < NCHUNK) {
            #pragma unroll
            for (int mi = 0; mi < 4; ++mi) {
                xr0[mi] = *(const float4*)(xb + (size_t)mi * 16 * DMODEL + (kc + 1) * KC);
                xr1[mi] = *(const float4*)(xb + (size_t)mi * 16 * DMODEL + (kc + 1) * KC + 4);
            }
        }

        // B fragments from L2 + 48 MFMAs
        const ushort* bc = bsrc + (size_t)kc * BCH;
        #pragma unroll
        for (int nj = 0; nj < 4; ++nj) {
            short8v bh = *(const short8v*)(bc + nj * 128);
            short8v bv = *(const short8v*)(bc + WA_LO_OFF + nj * 128);
            #pragma unroll
            for (int mi = 0; mi < 4; ++mi) {
                acc[mi][nj] = __builtin_amdgcn_mfma_f32_16x16x32_bf16(av[mi], bh, acc[mi][nj], 0, 0, 0);
                acc[mi][nj] = __builtin_amdgcn_mfma_f32_16x16x32_bf16(ah[mi], bv, acc[mi][nj], 0, 0, 0);
                acc[mi][nj] = __builtin_amdgcn_mfma_f32_16x16x32_bf16(ah[mi], bh, acc[mi][nj], 0, 0, 0);
            }
        }
    }

    // epilogue: tanh + ae-weighted reduce.
    // C/D map (HW-verified): row = mi*16 + g*4 + e, col = wid*64 + nj*16 + n
    float bav[4], aev[4];
    #pragma unroll
    for (int nj = 0; nj < 4; ++nj) {
        int c = wid * 64 + nj * 16 + n;
        bav[nj] = ba[c];
        aev[nj] = ae[c];
    }
    #pragma unroll
    for (int mi = 0; mi < 4; ++mi) {
        float zp[4] = {0.f, 0.f, 0.f, 0.f};
        #pragma unroll
        for (int nj = 0; nj < 4; ++nj)
            #pragma unroll
            for (int e = 0; e < 4; ++e)
                zp[e] += fast_tanh(acc[mi][nj][e] + bav[nj]) * aev[nj];
        #pragma unroll
        for (int off = 8; off >= 1; off >>= 1)
            #pragma unroll
            for (int e = 0; e < 4; ++e)
                zp[e] += __shfl_xor(zp[e], off, 64);
        if (n == 0)
            *(float4*)&zb[wid][mi * 16 + g * 4] = make_float4(zp[0], zp[1], zp[2], zp[3]);
    }
    __syncthreads();
    if (tid < MT)
        z[m0 + tid] = (zb[0][tid] + zb[1][tid]) + (zb[2][tid] + zb[3][tid]);
}

// K2: in-place softmax over SEQ per batch.
__global__ __launch_bounds__(256)
void softmax_kernel(float* __restrict__ zw) {
    __shared__ float red[4];
    __shared__ float bcast;
    const int b = blockIdx.x, tid = threadIdx.x;
    float* row = zw + (size_t)b * SEQ;

    float zi[8];
    #pragma unroll
    for (int i = 0; i < 8; ++i) zi[i] = row[tid + i * 256];

    float m = -3.0e38f;
    #pragma unroll
    for (int i = 0; i < 8; ++i) m = fmaxf(m, zi[i]);
    #pragma unroll
    for (int off = 32; off >= 1; off >>= 1) m = fmaxf(m, __shfl_xor(m, off, 64));
    if ((tid & 63) == 0) red[tid >> 6] = m;
    __syncthreads();
    if (tid == 0) bcast = fmaxf(fmaxf(red[0], red[1]), fmaxf(red[2], red[3]));
    __syncthreads();
    m = bcast;

    float s = 0.f;
    #pragma unroll
    for (int i = 0; i < 8; ++i) { zi[i] = expf(zi[i] - m); s += zi[i]; }
    #pragma unroll
    for (int off = 32; off >= 1; off >>= 1) s += __shfl_xor(s, off, 64);
    __syncthreads();
    if ((tid & 63) == 0) red[tid >> 6] = s;
    __syncthreads();
    if (tid == 0) bcast = 1.f / (red[0] + red[1] + red[2] + red[3]);
    __syncthreads();
    float inv = bcast;

    #pragma unroll
    for (int i = 0; i < 8; ++i) row[tid + i * 256] = zi[i] * inv;
}

// K3a: bf16 pool partials: partials[sc][b][f] = sum_{s in chunk} w[s]*Xh[b,s,f]
#define PCHUNK 256
__global__ __launch_bounds__(512)
void pool_bf16_kernel(const ushort* __restrict__ Xh, const float* __restrict__ w,
                      float* __restrict__ partials) {
    __shared__ float wl[PCHUNK];
    __shared__ float2 accs[512];
    const int b  = blockIdx.y;
    const int sc = blockIdx.x;       // 0..7
    const int t  = threadIdx.x;
    const int u  = t & 255;          // uint idx: features 2u, 2u+1
    const int p  = t >> 8;           // row parity
    const int s0 = sc * PCHUNK;
    if (t < PCHUNK) wl[t] = w[(size_t)b * SEQ + s0 + t];
    __syncthreads();
    const uint* xp = (const uint*)(Xh + ((size_t)b * SEQ + s0 + p) * DMODEL) + u;
    float a0 = 0.f, a1 = 0.f;
    #pragma unroll 8
    for (int s = 0; s < PCHUNK; s += 2) {
        uint v   = xp[(size_t)s * (DMODEL / 2)];
        float ws = wl[s + p];
        a0 = fmaf(__uint_as_float(v << 16), ws, a0);
        a1 = fmaf(__uint_as_float(v & 0xFFFF0000u), ws, a1);
    }
    accs[t] = make_float2(a0, a1);
    __syncthreads();
    if (t < 256) {
        float2 x0 = accs[t], x1 = accs[t + 256];
        *(float2*)&partials[((size_t)sc * BATCH + b) * DMODEL + 2 * t] =
            make_float2(x0.x + x1.x, x0.y + x1.y);
    }
}

// K3b: out[b][f] = sum_sc partials[sc][b][f]
__global__ __launch_bounds__(512)
void pool_reduce_kernel(const float* __restrict__ partials, float* __restrict__ out) {
    int i = blockIdx.x * 512 + threadIdx.x;   // 32768
    float s = 0.f;
    #pragma unroll
    for (int c = 0; c < 8; ++c)
        s += partials[(size_t)c * BATCH * DMODEL + i];
    out[i] = s;
}

// fallback fp32 pool (if ws too small): needs memset + atomics
__global__ __launch_bounds__(512)
void pool_fp32_kernel(const float* __restrict__ X, const float* __restrict__ w,
                      float* __restrict__ out) {
    __shared__ float wl[PCHUNK];
    const int b  = blockIdx.y;
    const int sc = blockIdx.x;
    const int f  = threadIdx.x;
    const int s0 = sc * PCHUNK;
    if (f < PCHUNK) wl[f] = w[(size_t)b * SEQ + s0 + f];
    __syncthreads();
    const float* xp = X + ((size_t)b * SEQ + s0) * DMODEL + f;
    float a0 = 0.f, a1 = 0.f, a2 = 0.f, a3 = 0.f;
    #pragma unroll 4
    for (int s = 0; s < PCHUNK; s += 4) {
        a0 = fmaf(xp[(size_t)(s + 0) * DMODEL], wl[s + 0], a0);
        a1 = fmaf(xp[(size_t)(s + 1) * DMODEL], wl[s + 1], a1);
        a2 = fmaf(xp[(size_t)(s + 2) * DMODEL], wl[s + 2], a2);
        a3 = fmaf(xp[(size_t)(s + 3) * DMODEL], wl[s + 3], a3);
    }
    atomicAdd(&out[b * DMODEL + f], (a0 + a1) + (a2 + a3));
}

extern "C" void kernel_launch(void* const* d_in, const int* in_sizes, int n_in,
                              void* d_out, int out_size, void* d_ws, size_t ws_size,
                              hipStream_t stream) {
    const float* X  = (const float*)d_in[0];
    const float* Wa = (const float*)d_in[1];
    const float* ba = (const float*)d_in[2];
    const float* ae = (const float*)d_in[3];
    float* out  = (float*)d_out;
    float* feat = out;                       // [64][512]
    float* wgt  = out + BATCH * DMODEL;      // [64][2048]; z pre-softmax

    ushort* wa_cvt = (ushort*)d_ws;          // 512 KB
    const bool big_ws = ws_size >= WS_NEED;
    ushort* Xh      = big_ws ? (ushort*)((char*)d_ws + XH_OFF)  : nullptr;
    float* partials = big_ws ? (float*)((char*)d_ws + PART_OFF) : nullptr;

    wa_convert_kernel<<<ATT * DMODEL / 256, 256, 0, stream>>>(Wa, wa_cvt);
    scores_mfma_kernel<<<M_TOTAL / MT, 256, 0, stream>>>(X, wa_cvt, ba, ae, wgt, Xh);
    softmax_kernel<<<BATCH, 256, 0, stream>>>(wgt);
    if (big_ws) {
        pool_bf16_kernel<<<dim3(SEQ / PCHUNK, BATCH), 512, 0, stream>>>(Xh, wgt, partials);
        pool_reduce_kernel<<<BATCH * DMODEL / 512, 512, 0, stream>>>(partials, feat);
    } else {
        hipMemsetAsync(feat, 0, BATCH * DMODEL * sizeof(float), stream);
        pool_fp32_kernel<<<dim3(SEQ / PCHUNK, BATCH), 512, 0, stream>>>(X, wgt, feat);
    }
}